// Round 1
// baseline (604.658 us; speedup 1.0000x reference)
//
#include <hip/hip_runtime.h>
#include <hip/hip_bf16.h>
#include <stdint.h>

#define E_EDGES 500000
#define DN 128   // D_NODE
#define DE 64    // D_EDGE
#define DI 320   // 2*DN + DE
#define DH 256   // D_HID
#define DO 64    // D_OUT
#define BE 64    // edges per block
#define X_LD 328 // 320 + 8 pad (bf16 elems) -> 656B row stride, 2-way banks
#define H_LD 264 // 256 + 8 pad             -> 528B row stride, 2-way banks

typedef __attribute__((ext_vector_type(8))) short short8;
typedef __attribute__((ext_vector_type(4))) short short4v;
typedef __attribute__((ext_vector_type(4))) float f32x4;

__device__ __forceinline__ short f2bf(float f) {
    union { float f; uint32_t u; } v; v.f = f;
    uint32_t r = (v.u + 0x7FFFu + ((v.u >> 16) & 1u)) >> 16;  // RNE
    return (short)(uint16_t)r;
}

// Transpose W1 [320][256] -> W1T [256][320] bf16, W2 [256][64] -> W2T [64][256] bf16
__global__ void convert_weights(const float* __restrict__ W1, const float* __restrict__ W2,
                                short* __restrict__ W1T, short* __restrict__ W2T) {
    int idx = blockIdx.x * 256 + threadIdx.x;
    if (idx < DI * DH) {
        int k = idx / DH, n = idx % DH;
        W1T[n * DI + k] = f2bf(W1[idx]);
    } else if (idx < DI * DH + DH * DO) {
        int i2 = idx - DI * DH;
        int k = i2 / DO, n = i2 % DO;
        W2T[n * DH + k] = f2bf(W2[i2]);
    }
}

__global__ __launch_bounds__(256, 2) void edge_mlp(
    const float* __restrict__ node_feats, const int* __restrict__ eidx,
    const float* __restrict__ edge_attr, const short* __restrict__ W1T,
    const float* __restrict__ b1, const short* __restrict__ W2T,
    const float* __restrict__ b2, float* __restrict__ out)
{
    // x tile [64][328] bf16 (42KB); reused as h tile [64][264] bf16 after layer 1
    __shared__ __align__(16) short lds[BE * X_LD];

    const int tid  = threadIdx.x;
    const int lane = tid & 63;
    const int wv   = tid >> 6;      // wave id 0..3
    const int lr   = lane & 15;     // row/col selector within fragment
    const int lk   = lane >> 4;     // k-group 0..3
    const long e0  = (long)blockIdx.x * BE;

    // ---- gather x = [nf[row] | nf[col] | ea] -> bf16 LDS; float4 granularity ----
    #pragma unroll
    for (int it = 0; it < 20; ++it) {           // 64 edges * 80 float4 chunks / 256 thr
        int c = it * 256 + tid;
        int e = c / 80;
        int k = (c % 80) * 4;
        long ge = e0 + e;
        float4 v = make_float4(0.f, 0.f, 0.f, 0.f);
        if (ge < E_EDGES) {
            if (k < DN) {
                int r = eidx[ge];
                v = *(const float4*)(node_feats + (long)r * DN + k);
            } else if (k < 2 * DN) {
                int cc = eidx[E_EDGES + ge];
                v = *(const float4*)(node_feats + (long)cc * DN + (k - DN));
            } else {
                v = *(const float4*)(edge_attr + ge * DE + (k - 2 * DN));
            }
        }
        short4v s;
        s.x = f2bf(v.x); s.y = f2bf(v.y); s.z = f2bf(v.z); s.w = f2bf(v.w);
        *(short4v*)(&lds[e * X_LD + k]) = s;
    }
    __syncthreads();

    // ---- layer 1: h[64][256] = relu(x @ W1 + b1); wave wv owns cols wv*64..+63 ----
    f32x4 acc[4][4];
    #pragma unroll
    for (int m = 0; m < 4; ++m)
        #pragma unroll
        for (int n = 0; n < 4; ++n)
            acc[m][n] = (f32x4){0.f, 0.f, 0.f, 0.f};

    for (int k0 = 0; k0 < DI; k0 += 32) {
        short8 a[4], b[4];
        #pragma unroll
        for (int m = 0; m < 4; ++m)
            a[m] = *(const short8*)(&lds[(m * 16 + lr) * X_LD + k0 + lk * 8]);
        #pragma unroll
        for (int n = 0; n < 4; ++n)
            b[n] = *(const short8*)(W1T + (long)(wv * 64 + n * 16 + lr) * DI + k0 + lk * 8);
        #pragma unroll
        for (int m = 0; m < 4; ++m)
            #pragma unroll
            for (int n = 0; n < 4; ++n)
                acc[m][n] = __builtin_amdgcn_mfma_f32_16x16x32_bf16(a[m], b[n], acc[m][n], 0, 0, 0);
    }
    __syncthreads();   // all x reads complete before overwriting lds with h

    #pragma unroll
    for (int n = 0; n < 4; ++n) {
        int col = wv * 64 + n * 16 + lr;
        float bias = b1[col];
        #pragma unroll
        for (int m = 0; m < 4; ++m) {
            #pragma unroll
            for (int j = 0; j < 4; ++j) {
                int row = m * 16 + lk * 4 + j;            // C layout: row=(l>>4)*4+j
                float hv = acc[m][n][j] + bias;
                lds[row * H_LD + col] = f2bf(fmaxf(hv, 0.f));
            }
        }
    }
    __syncthreads();

    // ---- layer 2: out[64][64] = h @ W2 + b2; wave wv owns edge rows wv*16..+15 ----
    f32x4 acc2[4];
    #pragma unroll
    for (int n = 0; n < 4; ++n) acc2[n] = (f32x4){0.f, 0.f, 0.f, 0.f};

    for (int k0 = 0; k0 < DH; k0 += 32) {
        short8 a = *(const short8*)(&lds[(wv * 16 + lr) * H_LD + k0 + lk * 8]);
        short8 b[4];
        #pragma unroll
        for (int n = 0; n < 4; ++n)
            b[n] = *(const short8*)(W2T + (long)(n * 16 + lr) * DH + k0 + lk * 8);
        #pragma unroll
        for (int n = 0; n < 4; ++n)
            acc2[n] = __builtin_amdgcn_mfma_f32_16x16x32_bf16(a, b[n], acc2[n], 0, 0, 0);
    }

    #pragma unroll
    for (int n = 0; n < 4; ++n) {
        int c = n * 16 + lr;
        float bias = b2[c];
        #pragma unroll
        for (int j = 0; j < 4; ++j) {
            long ge = e0 + wv * 16 + lk * 4 + j;
            if (ge < E_EDGES)
                out[ge * DO + c] = acc2[n][j] + bias;
        }
    }
}

extern "C" void kernel_launch(void* const* d_in, const int* in_sizes, int n_in,
                              void* d_out, int out_size, void* d_ws, size_t ws_size,
                              hipStream_t stream) {
    const float* node_feats = (const float*)d_in[0];
    const int*   eidx       = (const int*)d_in[1];
    const float* edge_attr  = (const float*)d_in[2];
    const float* W1         = (const float*)d_in[3];
    const float* b1         = (const float*)d_in[4];
    const float* W2         = (const float*)d_in[5];
    const float* b2         = (const float*)d_in[6];
    float* out = (float*)d_out;

    short* W1T = (short*)d_ws;             // 256*320 bf16 = 160KB
    short* W2T = W1T + DI * DH;            //  64*256 bf16 =  32KB

    convert_weights<<<(DI * DH + DH * DO + 255) / 256, 256, 0, stream>>>(W1, W2, W1T, W2T);
    edge_mlp<<<(E_EDGES + BE - 1) / BE, 256, 0, stream>>>(
        node_feats, eidx, edge_attr, W1T, b1, W2T, b2, out);
}

// Round 2
// 331.904 us; speedup vs baseline: 1.8218x; 1.8218x over previous
//
#include <hip/hip_runtime.h>
#include <hip/hip_bf16.h>
#include <stdint.h>

#define E_EDGES 500000
#define DN 128   // D_NODE
#define DE 64    // D_EDGE
#define DI 320   // 2*DN + DE
#define DH 256   // D_HID
#define DO 64    // D_OUT
#define BE 64    // edges per block

typedef __attribute__((ext_vector_type(8))) short short8;
typedef __attribute__((ext_vector_type(4))) short short4v;
typedef __attribute__((ext_vector_type(4))) float f32x4;

__device__ __forceinline__ short f2bf(float f) {
    __hip_bfloat16 h = __float2bfloat16(f);
    union { __hip_bfloat16 h; short s; } u; u.h = h;
    return u.s;
}

// W1 [320][256] -> W1T [256][320] bf16 ; W2 [256][64] -> W2T [64][256] bf16
__global__ void convert_weights(const float* __restrict__ W1, const float* __restrict__ W2,
                                short* __restrict__ W1T, short* __restrict__ W2T) {
    int idx = blockIdx.x * 256 + threadIdx.x;
    if (idx < DI * DH) {
        int k = idx / DH, n = idx % DH;
        W1T[n * DI + k] = f2bf(W1[idx]);
    } else if (idx < DI * DH + DH * DO) {
        int i2 = idx - DI * DH;
        int k = i2 / DO, n = i2 % DO;
        W2T[n * DH + k] = f2bf(W2[i2]);
    }
}

__global__ __launch_bounds__(256, 4) void edge_mlp(
    const float* __restrict__ node_feats, const int* __restrict__ eidx,
    const float* __restrict__ edge_attr, const short* __restrict__ W1T,
    const float* __restrict__ b1, const short* __restrict__ W2T,
    const float* __restrict__ b2, float* __restrict__ out)
{
    // x tile [64][320] bf16, XOR-swizzled (byte ^= (row&7)<<4), 40960B = 4 blocks/CU.
    // Reused as h tile [64][256] bf16 (also swizzled) after layer 1.
    __shared__ __align__(128) short xbuf[BE * DI];

    const int tid  = threadIdx.x;
    const int lane = tid & 63;
    const int wv   = tid >> 6;      // wave 0..3
    const int lr   = lane & 15;
    const int lk   = lane >> 4;     // k-group 0..3
    const long e0  = (long)blockIdx.x * BE;
    char* xb = (char*)xbuf;

    // ---- gather: thread (e = tid>>2, q = tid&3) owns quarter q of edge e's row ----
    {
        const int q = tid & 3;
        const int e = tid >> 2;
        long ge = e0 + e;
        if (ge < E_EDGES) {
            int ri = eidx[ge];
            int ci = eidx[E_EDGES + ge];
            const float4* sr = (const float4*)(node_feats + (long)ri * DN) + q;
            const float4* sc = (const float4*)(node_feats + (long)ci * DN) + q;
            const float4* se = (const float4*)(edge_attr + ge * DE) + q;
            #pragma unroll
            for (int i = 0; i < 8; ++i) {               // nf[row]: chunks q+4i
                float4 v = sr[i * 4];
                int c = q + 4 * i;
                short4v s = {f2bf(v.x), f2bf(v.y), f2bf(v.z), f2bf(v.w)};
                *(short4v*)(xb + ((e * 640 + c * 8) ^ ((e & 7) << 4))) = s;
            }
            #pragma unroll
            for (int i = 0; i < 8; ++i) {               // nf[col]: chunks 32+q+4i
                float4 v = sc[i * 4];
                int c = 32 + q + 4 * i;
                short4v s = {f2bf(v.x), f2bf(v.y), f2bf(v.z), f2bf(v.w)};
                *(short4v*)(xb + ((e * 640 + c * 8) ^ ((e & 7) << 4))) = s;
            }
            #pragma unroll
            for (int i = 0; i < 4; ++i) {               // edge_attr: chunks 64+q+4i
                float4 v = se[i * 4];
                int c = 64 + q + 4 * i;
                short4v s = {f2bf(v.x), f2bf(v.y), f2bf(v.z), f2bf(v.w)};
                *(short4v*)(xb + ((e * 640 + c * 8) ^ ((e & 7) << 4))) = s;
            }
        }
        // tail edges: garbage x -> garbage only in dead accumulator columns; final store is guarded
    }
    __syncthreads();

    // ---- layer 1 (swapped operands): acc[m][n] = W1T-tile(n) x X-tile(m)^T = h^T ----
    // D: col(l&15) = edge offset in m-group, row(lk*4+j) = h-col offset in n-group
    f32x4 acc[4][4];
    #pragma unroll
    for (int m = 0; m < 4; ++m)
        #pragma unroll
        for (int n = 0; n < 4; ++n)
            acc[m][n] = (f32x4){0.f, 0.f, 0.f, 0.f};

    #pragma unroll
    for (int k0 = 0; k0 < DI; k0 += 32) {
        short8 xa[4], wb[4];
        #pragma unroll
        for (int m = 0; m < 4; ++m) {
            int row = m * 16 + lr;
            xa[m] = *(const short8*)(xb + ((row * 640 + k0 * 2 + lk * 16) ^ ((row & 7) << 4)));
        }
        #pragma unroll
        for (int n = 0; n < 4; ++n)
            wb[n] = *(const short8*)(W1T + (long)(wv * 64 + n * 16 + lr) * DI + k0 + lk * 8);
        #pragma unroll
        for (int m = 0; m < 4; ++m)
            #pragma unroll
            for (int n = 0; n < 4; ++n)
                acc[m][n] = __builtin_amdgcn_mfma_f32_16x16x32_bf16(wb[n], xa[m], acc[m][n], 0, 0, 0);
    }
    __syncthreads();   // all x reads done before overwriting with h

    // ---- h = relu(acc + b1), bf16, back to LDS: per lane 4 consecutive h-cols -> ds_write_b64
    #pragma unroll
    for (int n = 0; n < 4; ++n) {
        float4 bb = *(const float4*)(b1 + wv * 64 + n * 16 + lk * 4);
        #pragma unroll
        for (int m = 0; m < 4; ++m) {
            int edge = m * 16 + lr;
            short4v hs;
            hs.x = f2bf(fmaxf(acc[m][n][0] + bb.x, 0.f));
            hs.y = f2bf(fmaxf(acc[m][n][1] + bb.y, 0.f));
            hs.z = f2bf(fmaxf(acc[m][n][2] + bb.z, 0.f));
            hs.w = f2bf(fmaxf(acc[m][n][3] + bb.w, 0.f));
            int hcol = wv * 64 + n * 16 + lk * 4;
            *(short4v*)(xb + ((edge * 512 + hcol * 2) ^ ((edge & 7) << 4))) = hs;
        }
    }
    __syncthreads();

    // ---- layer 2 (swapped): acc2[n] = W2T-tile(n) x h-tile(wv)^T -> out^T fragment ----
    f32x4 acc2[4];
    #pragma unroll
    for (int n = 0; n < 4; ++n) acc2[n] = (f32x4){0.f, 0.f, 0.f, 0.f};

    {
        const int edge = wv * 16 + lr;
        #pragma unroll
        for (int k0 = 0; k0 < DH; k0 += 32) {
            short8 hb = *(const short8*)(xb + ((edge * 512 + k0 * 2 + lk * 16) ^ ((edge & 7) << 4)));
            #pragma unroll
            for (int n = 0; n < 4; ++n) {
                short8 wb2 = *(const short8*)(W2T + (long)(n * 16 + lr) * DH + k0 + lk * 8);
                acc2[n] = __builtin_amdgcn_mfma_f32_16x16x32_bf16(wb2, hb, acc2[n], 0, 0, 0);
            }
        }
    }

    // ---- store: lane holds 4 consecutive out-cols per n -> float4 stores, fully coalesced
    {
        long ge2 = e0 + wv * 16 + lr;
        if (ge2 < E_EDGES) {
            float* op = out + ge2 * DO;
            #pragma unroll
            for (int n = 0; n < 4; ++n) {
                float4 bb = *(const float4*)(b2 + n * 16 + lk * 4);
                float4 o4;
                o4.x = acc2[n][0] + bb.x;
                o4.y = acc2[n][1] + bb.y;
                o4.z = acc2[n][2] + bb.z;
                o4.w = acc2[n][3] + bb.w;
                *(float4*)(op + n * 16 + lk * 4) = o4;
            }
        }
    }
}

extern "C" void kernel_launch(void* const* d_in, const int* in_sizes, int n_in,
                              void* d_out, int out_size, void* d_ws, size_t ws_size,
                              hipStream_t stream) {
    const float* node_feats = (const float*)d_in[0];
    const int*   eidx       = (const int*)d_in[1];
    const float* edge_attr  = (const float*)d_in[2];
    const float* W1         = (const float*)d_in[3];
    const float* b1         = (const float*)d_in[4];
    const float* W2         = (const float*)d_in[5];
    const float* b2         = (const float*)d_in[6];
    float* out = (float*)d_out;

    short* W1T = (short*)d_ws;             // 256*320 bf16 = 160KB
    short* W2T = W1T + DI * DH;            //  64*256 bf16 =  32KB

    convert_weights<<<(DI * DH + DH * DO + 255) / 256, 256, 0, stream>>>(W1, W2, W1T, W2T);
    edge_mlp<<<(E_EDGES + BE - 1) / BE, 256, 0, stream>>>(
        node_feats, eidx, edge_attr, W1T, b1, W2T, b2, out);
}

// Round 3
// 267.635 us; speedup vs baseline: 2.2593x; 1.2401x over previous
//
#include <hip/hip_runtime.h>
#include <hip/hip_bf16.h>
#include <stdint.h>

#define E_EDGES 500000
#define NNODES  50000
#define DN 128
#define DE 64
#define DH 256
#define DO 64
#define BE 32            // edges per block; 500000/32 = 15625 exact, no tail

typedef __attribute__((ext_vector_type(8))) short short8;
typedef __attribute__((ext_vector_type(4))) short short4v;
typedef __attribute__((ext_vector_type(4))) float f32x4;

__device__ __forceinline__ short f2bf(float f) {
    union { float f; uint32_t u; } v; v.f = f;
    uint32_t r = (v.u + 0x7FFFu + ((v.u >> 16) & 1u)) >> 16;  // RNE
    return (short)(uint16_t)r;
}
__device__ __forceinline__ float bf2f(short s) {
    union { uint32_t u; float f; } v; v.u = ((uint32_t)(uint16_t)s) << 16;
    return v.f;
}

// WcatT[512][128]: c<256 -> W1[k][c] (W1a^T), c>=256 -> W1[128+k][c-256] (W1b^T)
// W1cT [256][64] : W1[256+k][c] ; W2T [64][256] : W2[k][n]
__global__ void convert_weights(const float* __restrict__ W1, const float* __restrict__ W2,
                                short* __restrict__ WcatT, short* __restrict__ W1cT,
                                short* __restrict__ W2T) {
    int idx = blockIdx.x * 256 + threadIdx.x;
    if (idx < 512 * 128) {
        int c = idx >> 7, k = idx & 127;
        WcatT[idx] = f2bf(W1[(c < 256 ? k : k + 128) * DH + (c & 255)]);
    } else if (idx < 512 * 128 + 256 * 64) {
        int i = idx - 512 * 128;
        int c = i >> 6, k = i & 63;
        W1cT[i] = f2bf(W1[(256 + k) * DH + c]);
    } else if (idx < 512 * 128 + 256 * 64 + 64 * 256) {
        int i = idx - 512 * 128 - 256 * 64;
        int n = i >> 8, k = i & 255;
        W2T[i] = f2bf(W2[k * DO + n]);
    }
}

// PQ[50000][512] bf16 = nf @ [W1a | W1b]
__global__ __launch_bounds__(256, 4) void node_gemm(
    const float* __restrict__ nf, const short* __restrict__ WcatT, short* __restrict__ PQ)
{
    __shared__ __align__(16) short xt[64 * 128];   // [64][128] bf16, XOR-swizzled, 16KB
    const int tid = threadIdx.x, lane = tid & 63, wv = tid >> 6;
    const int lr = lane & 15, lk = lane >> 4;
    const int r0 = blockIdx.x * 64;
    const int cb = blockIdx.y * 256;
    char* xb = (char*)xt;

    {   // stage nf tile (rows clamped; garbage rows never stored)
        int r = tid >> 2, q = tid & 3;
        int gr = r0 + r; if (gr > NNODES - 1) gr = NNODES - 1;
        const float4* src = (const float4*)(nf + (long)gr * DN) + q * 8;
        #pragma unroll
        for (int i = 0; i < 4; ++i) {
            float4 a = src[2 * i], b = src[2 * i + 1];
            short8 s = { f2bf(a.x), f2bf(a.y), f2bf(a.z), f2bf(a.w),
                         f2bf(b.x), f2bf(b.y), f2bf(b.z), f2bf(b.w) };
            *(short8*)(xb + ((r * 256 + q * 64 + i * 16) ^ ((r & 7) << 4))) = s;
        }
    }
    __syncthreads();

    f32x4 acc[4][4];
    #pragma unroll
    for (int m = 0; m < 4; ++m)
        #pragma unroll
        for (int n = 0; n < 4; ++n)
            acc[m][n] = (f32x4){0.f, 0.f, 0.f, 0.f};

    #pragma unroll
    for (int kt = 0; kt < 4; ++kt) {
        short8 a[4], w[4];
        #pragma unroll
        for (int m = 0; m < 4; ++m) {
            int row = 16 * m + lr;
            a[m] = *(const short8*)(xb + ((row * 256 + kt * 64 + lk * 16) ^ ((row & 7) << 4)));
        }
        #pragma unroll
        for (int n = 0; n < 4; ++n)
            w[n] = *(const short8*)(WcatT + (long)(cb + wv * 64 + n * 16 + lr) * 128 + kt * 32 + lk * 8);
        #pragma unroll
        for (int m = 0; m < 4; ++m)
            #pragma unroll
            for (int n = 0; n < 4; ++n)
                acc[m][n] = __builtin_amdgcn_mfma_f32_16x16x32_bf16(w[n], a[m], acc[m][n], 0, 0, 0);
    }

    #pragma unroll
    for (int m = 0; m < 4; ++m) {
        int row = r0 + 16 * m + lr;
        if (row < NNODES) {
            #pragma unroll
            for (int n = 0; n < 4; ++n) {
                short4v s = { f2bf(acc[m][n][0]), f2bf(acc[m][n][1]),
                              f2bf(acc[m][n][2]), f2bf(acc[m][n][3]) };
                *(short4v*)(PQ + (long)row * 512 + cb + wv * 64 + n * 16 + lk * 4) = s;
            }
        }
    }
}

// per-edge: h = relu(P[row] + Q[col] + ea@W1c + b1); out = h@W2 + b2
__global__ __launch_bounds__(256, 6) void edge_mlp(
    const int* __restrict__ eidx, const float* __restrict__ ea,
    const short* __restrict__ PQ, const short* __restrict__ W1cT,
    const float* __restrict__ b1, const short* __restrict__ W2T,
    const float* __restrict__ b2, float* __restrict__ out)
{
    __shared__ __align__(16) short st[BE * 256];  // S then h, [32][256] bf16 swizzled, 16KB
    const int tid = threadIdx.x, lane = tid & 63, wv = tid >> 6;
    const int lr = lane & 15, lk = lane >> 4;
    const long e0 = (long)blockIdx.x * BE;
    char* sb = (char*)st;

    {   // Phase A: S = P[row] + Q[col]  (8 threads/edge, 32 cols each)
        int e = tid >> 3, r = tid & 7;
        long ge = e0 + e;
        int ri = eidx[ge];
        int ci = eidx[E_EDGES + ge];
        const short8* ps = (const short8*)(PQ + (long)ri * 512) + r * 4;
        const short8* qs = (const short8*)(PQ + (long)ci * 512 + 256) + r * 4;
        #pragma unroll
        for (int i = 0; i < 4; ++i) {
            short8 p = ps[i], q = qs[i];
            short8 s;
            #pragma unroll
            for (int j = 0; j < 8; ++j)
                s[j] = f2bf(bf2f(p[j]) + bf2f(q[j]));
            *(short8*)(sb + ((e * 512 + r * 64 + i * 16) ^ ((e & 7) << 4))) = s;
        }
    }
    __syncthreads();

    // Phase B: acc = ea @ W1c  (swapped mfma: D col = edge)
    f32x4 acc[2][4];
    #pragma unroll
    for (int m = 0; m < 2; ++m)
        #pragma unroll
        for (int n = 0; n < 4; ++n)
            acc[m][n] = (f32x4){0.f, 0.f, 0.f, 0.f};

    #pragma unroll
    for (int kt = 0; kt < 2; ++kt) {
        short8 w[4], eb[2];
        #pragma unroll
        for (int n = 0; n < 4; ++n)
            w[n] = *(const short8*)(W1cT + (wv * 64 + n * 16 + lr) * 64 + kt * 32 + lk * 8);
        #pragma unroll
        for (int m = 0; m < 2; ++m) {
            const float4* s = (const float4*)(ea + (e0 + 16 * m + lr) * DE + kt * 32 + lk * 8);
            float4 x = s[0], y = s[1];
            eb[m] = (short8){ f2bf(x.x), f2bf(x.y), f2bf(x.z), f2bf(x.w),
                              f2bf(y.x), f2bf(y.y), f2bf(y.z), f2bf(y.w) };
        }
        #pragma unroll
        for (int m = 0; m < 2; ++m)
            #pragma unroll
            for (int n = 0; n < 4; ++n)
                acc[m][n] = __builtin_amdgcn_mfma_f32_16x16x32_bf16(w[n], eb[m], acc[m][n], 0, 0, 0);
    }

    // Phase C: h = relu(acc + S + b1) written in place over S
    #pragma unroll
    for (int n = 0; n < 4; ++n) {
        float4 bb = *(const float4*)(b1 + wv * 64 + n * 16 + lk * 4);
        #pragma unroll
        for (int m = 0; m < 2; ++m) {
            int e = 16 * m + lr;
            int hc = wv * 64 + n * 16 + lk * 4;
            char* addr = sb + ((e * 512 + hc * 2) ^ ((e & 7) << 4));
            short4v s = *(short4v*)addr;
            short4v hb;
            hb.x = f2bf(fmaxf(acc[m][n][0] + bb.x + bf2f(s.x), 0.f));
            hb.y = f2bf(fmaxf(acc[m][n][1] + bb.y + bf2f(s.y), 0.f));
            hb.z = f2bf(fmaxf(acc[m][n][2] + bb.z + bf2f(s.z), 0.f));
            hb.w = f2bf(fmaxf(acc[m][n][3] + bb.w + bf2f(s.w), 0.f));
            *(short4v*)addr = hb;
        }
    }
    __syncthreads();

    // Phase D: out = h @ W2 + b2  (wave owns out-cols 16*wv..+15)
    f32x4 acc2[2];
    acc2[0] = (f32x4){0.f, 0.f, 0.f, 0.f};
    acc2[1] = (f32x4){0.f, 0.f, 0.f, 0.f};

    #pragma unroll
    for (int kt = 0; kt < 8; ++kt) {
        short8 w2 = *(const short8*)(W2T + (wv * 16 + lr) * 256 + kt * 32 + lk * 8);
        #pragma unroll
        for (int m = 0; m < 2; ++m) {
            int e = 16 * m + lr;
            short8 hb = *(const short8*)(sb + ((e * 512 + kt * 64 + lk * 16) ^ ((e & 7) << 4)));
            acc2[m] = __builtin_amdgcn_mfma_f32_16x16x32_bf16(w2, hb, acc2[m], 0, 0, 0);
        }
    }

    #pragma unroll
    for (int m = 0; m < 2; ++m) {
        float4 bb = *(const float4*)(b2 + wv * 16 + lk * 4);
        long ge = e0 + 16 * m + lr;
        float4 o;
        o.x = acc2[m][0] + bb.x;
        o.y = acc2[m][1] + bb.y;
        o.z = acc2[m][2] + bb.z;
        o.w = acc2[m][3] + bb.w;
        *(float4*)(out + ge * DO + wv * 16 + lk * 4) = o;
    }
}

extern "C" void kernel_launch(void* const* d_in, const int* in_sizes, int n_in,
                              void* d_out, int out_size, void* d_ws, size_t ws_size,
                              hipStream_t stream) {
    const float* node_feats = (const float*)d_in[0];
    const int*   eidx       = (const int*)d_in[1];
    const float* edge_attr  = (const float*)d_in[2];
    const float* W1         = (const float*)d_in[3];
    const float* b1         = (const float*)d_in[4];
    const float* W2         = (const float*)d_in[5];
    const float* b2         = (const float*)d_in[6];
    float* out = (float*)d_out;

    short* WcatT = (short*)d_ws;            // 512*128
    short* W1cT  = WcatT + 512 * 128;       // 256*64
    short* W2T   = W1cT + 256 * 64;         // 64*256
    short* PQ    = W2T + 64 * 256;          // 50000*512 bf16 (~51.2MB)

    convert_weights<<<384, 256, 0, stream>>>(W1, W2, WcatT, W1cT, W2T);
    node_gemm<<<dim3(782, 2), 256, 0, stream>>>(node_feats, WcatT, PQ);
    edge_mlp<<<E_EDGES / BE, 256, 0, stream>>>(eidx, edge_attr, PQ, W1cT, b1, W2T, b2, out);
}